// Round 6
// baseline (559.357 us; speedup 1.0000x reference)
//
#include <hip/hip_runtime.h>
#include <math.h>

#define NB 8
#define NS 1024
#define NV 32000
#define NROWS (NB * NS)          // 8192 = grid size, one block per row
#define N4 (NV / 4)              // 8000 float4 per row
#define FXSCALE 16777216.0f      // 2^24 fixed-point scale

// workspace layout (d_ws): [24 x u64 sums][24 x u32 counts][1 x u32 counter]
// memset to 0 each call (graph-capturable node).

__global__ __launch_bounds__(256)
void fused_loss_kernel(const float* __restrict__ logits,
                       const int* __restrict__ inp,
                       const int* __restrict__ tgt,
                       float* __restrict__ out,
                       unsigned long long* __restrict__ sums,
                       unsigned int* __restrict__ cnts,
                       unsigned int* __restrict__ ctr) {
    const int row = blockIdx.x;                 // 0 .. NROWS-1
    const float* rp = logits + (size_t)row * NV;
    const float4* rp4 = (const float4*)rp;      // normal cached loads (NO nt!)
    const int tid = threadIdx.x;

    // ---- uncentered exp-sum: no trans op in the serial dep chain ----
    float s0 = 0.f, s1 = 0.f;
    for (int i = tid; i < N4; i += 256) {
        float4 x = rp4[i];
        s0 += __expf(x.x) + __expf(x.y);        // dep chain: 1 add per iter
        s1 += __expf(x.z) + __expf(x.w);
    }
    float s = s0 + s1;

    #pragma unroll
    for (int off = 1; off < 64; off <<= 1)
        s += __shfl_xor(s, off, 64);

    __shared__ float ssum[4];
    __shared__ float blk_s;
    const int wave = tid >> 6, lane = tid & 63;
    if (lane == 0) ssum[wave] = s;
    __syncthreads();
    if (tid == 0) blk_s = (ssum[0] + ssum[1]) + (ssum[2] + ssum[3]);
    __syncthreads();
    const float S = blk_s;

    float nllv;
    if (S > 1.0e-30f && S < 3.0e38f) {          // fast path (block-uniform)
        nllv = __logf(S) - rp[tgt[row]];
    } else {
        // ---- fallback: centered two-pass (block-uniform; never for N(0,1)) ----
        float m = -INFINITY;
        for (int i = tid; i < N4; i += 256) {
            float4 x = rp4[i];
            m = fmaxf(m, fmaxf(fmaxf(x.x, x.y), fmaxf(x.z, x.w)));
        }
        #pragma unroll
        for (int off = 1; off < 64; off <<= 1)
            m = fmaxf(m, __shfl_xor(m, off, 64));
        __shared__ float smax[4];
        __shared__ float blk_m;
        if (lane == 0) smax[wave] = m;
        __syncthreads();
        if (tid == 0)
            blk_m = fmaxf(fmaxf(smax[0], smax[1]), fmaxf(smax[2], smax[3]));
        __syncthreads();
        const float M = blk_m;

        float c0 = 0.f, c1 = 0.f;
        for (int i = tid; i < N4; i += 256) {
            float4 x = rp4[i];
            c0 += __expf(x.x - M) + __expf(x.y - M);
            c1 += __expf(x.z - M) + __expf(x.w - M);
        }
        float c = c0 + c1;
        #pragma unroll
        for (int off = 1; off < 64; off <<= 1)
            c += __shfl_xor(c, off, 64);
        if (lane == 0) ssum[wave] = c;
        __syncthreads();
        __shared__ float blk_c;
        if (tid == 0) blk_c = (ssum[0] + ssum[1]) + (ssum[2] + ssum[3]);
        __syncthreads();
        nllv = M + __logf(blk_c) - rp[tgt[row]];
    }

    // ---- accumulate + last-block finalize (single dispatch, no tail kernels)
    if (tid == 0) {
        int tok = inp[row];
        int k = (tok == 4) ? 1 : (((unsigned)tok < 4u) ? 2 : 0); // reg/msk/spc
        int b = row >> 10;                                       // NS == 1024
        long long q = (long long)(nllv * FXSCALE);               // deterministic
        atomicAdd(&sums[b * 3 + k], (unsigned long long)q);
        atomicAdd(&cnts[b * 3 + k], 1u);
        __threadfence();
        unsigned int old = atomicAdd(ctr, 1u);
        if (old == (unsigned int)(gridDim.x - 1)) {
            const float W[3] = {1.0f, 1.0f, 0.01f};
            float loss_acc = 0.f;
            float sum_m[3] = {0.f, 0.f, 0.f};
            float sum_p[3] = {0.f, 0.f, 0.f};
            for (int bb = 0; bb < NB; ++bb) {
                float num = 0.f, tw = 0.f;
                #pragma unroll
                for (int kk = 0; kk < 3; ++kk) {
                    long long sll =
                        (long long)atomicAdd(&sums[bb * 3 + kk], 0ull);
                    unsigned int cn = atomicAdd(&cnts[bb * 3 + kk], 0u);
                    float sv = (float)((double)sll / 16777216.0);
                    float p = (cn > 0u) ? 1.f : 0.f;
                    float mean = (cn > 0u) ? (sv / (float)cn) : 0.f;
                    num += mean * W[kk] * p;
                    tw  += p * W[kk];
                    sum_m[kk] += mean;
                    sum_p[kk] += p;
                }
                loss_acc += num / tw;
            }
            out[0] = loss_acc / (float)NB;
            #pragma unroll
            for (int kk = 0; kk < 3; ++kk)
                out[1 + kk] = (sum_p[kk] > 0.f)
                                  ? (sum_m[kk] / fmaxf(sum_p[kk], 1.f))
                                  : 0.f;
        }
    }
}

// ---------------------------------------------------------------------------
extern "C" void kernel_launch(void* const* d_in, const int* in_sizes, int n_in,
                              void* d_out, int out_size, void* d_ws, size_t ws_size,
                              hipStream_t stream) {
    const float* logits = (const float*)d_in[0];   // [B,S,V] f32
    const int*   inp    = (const int*)d_in[1];     // [B,S] i32
    const int*   tgt    = (const int*)d_in[2];     // [B,S] i32
    float* out = (float*)d_out;                    // 4 f32

    unsigned long long* sums = (unsigned long long*)d_ws;        // 24 x u64
    unsigned int* cnts = (unsigned int*)(sums + NB * 3);         // 24 x u32
    unsigned int* ctr  = cnts + NB * 3;                          // 1 x u32

    (void)hipMemsetAsync(d_ws, 0, 512, stream);    // graph node, re-zeroed per call
    fused_loss_kernel<<<NROWS, 256, 0, stream>>>(logits, inp, tgt,
                                                 out, sums, cnts, ctr);
}

// Round 7
// 182.583 us; speedup vs baseline: 3.0636x; 3.0636x over previous
//
#include <hip/hip_runtime.h>
#include <math.h>

#define NB 8
#define NS 1024
#define NV 32000
#define N4 (NV / 4)              // 8000 float4 per row
// 8000 = 31*256 + 64: each thread does 31 uniform chunks; wave 0 takes the tail.

// ---------------------------------------------------------------------------
// Kernel 1: per-row logsumexp -> nll[row] = lse - logits[row, tgt[row]]
// One 256-thread block per row. Depth-2 software-pipelined float4 stream,
// uncentered exp-sum (no trans op in the serial accumulator chain), with a
// block-uniform centered two-pass fallback for over/underflow (never taken
// for sane logits; correctness-only).
// ---------------------------------------------------------------------------
__global__ __launch_bounds__(256)
void nll_kernel(const float* __restrict__ logits,
                const int* __restrict__ tgt,
                float* __restrict__ nll) {
    const int row = blockIdx.x;                 // 0 .. NB*NS-1
    const float* rp = logits + (size_t)row * NV;
    const float4* rp4 = (const float4*)rp;
    const int tid = threadIdx.x;

    // wave-uniform target logit: issue the (likely) HBM miss up front so it
    // completes under the stream instead of serializing the epilogue
    const float lt = rp[tgt[row]];

    // ---- depth-2 pipelined uncentered exp-sum ----
    float s0 = 0.f, s1 = 0.f;
    float4 a = rp4[tid];
    float4 b = rp4[tid + 256];
    int i = tid + 512;
    for (int it = 0; it < 29; ++it, i += 256) {
        float4 c = rp4[i];                      // load 2 ahead of consume
        s0 += __expf(a.x) + __expf(a.y);
        s1 += __expf(a.z) + __expf(a.w);
        a = b; b = c;
    }
    s0 += __expf(a.x) + __expf(a.y) + __expf(b.x) + __expf(b.y);
    s1 += __expf(a.z) + __expf(a.w) + __expf(b.z) + __expf(b.w);
    if (tid < 64) {                             // tail: last 64 float4
        float4 t = rp4[31 * 256 + tid];
        s0 += __expf(t.x) + __expf(t.y);
        s1 += __expf(t.z) + __expf(t.w);
    }
    float s = s0 + s1;

    #pragma unroll
    for (int off = 1; off < 64; off <<= 1)
        s += __shfl_xor(s, off, 64);

    __shared__ float ssum[4];
    __shared__ float blk_s;
    const int wave = tid >> 6, lane = tid & 63;
    if (lane == 0) ssum[wave] = s;
    __syncthreads();
    if (tid == 0) blk_s = (ssum[0] + ssum[1]) + (ssum[2] + ssum[3]);
    __syncthreads();
    const float S = blk_s;

    if (S > 1.0e-30f && S < 3.0e38f) {          // fast path (block-uniform)
        if (tid == 0) nll[row] = __logf(S) - lt;
        return;
    }

    // ---- fallback: centered two-pass (block-uniform, rare) ----
    float m = -INFINITY;
    for (int j = tid; j < N4; j += 256) {
        float4 x = rp4[j];
        m = fmaxf(m, fmaxf(fmaxf(x.x, x.y), fmaxf(x.z, x.w)));
    }
    #pragma unroll
    for (int off = 1; off < 64; off <<= 1)
        m = fmaxf(m, __shfl_xor(m, off, 64));
    __shared__ float smax[4];
    __shared__ float blk_m;
    if (lane == 0) smax[wave] = m;
    __syncthreads();
    if (tid == 0)
        blk_m = fmaxf(fmaxf(smax[0], smax[1]), fmaxf(smax[2], smax[3]));
    __syncthreads();
    const float M = blk_m;

    float c0 = 0.f, c1 = 0.f;
    for (int j = tid; j < N4; j += 256) {
        float4 x = rp4[j];
        c0 += __expf(x.x - M) + __expf(x.y - M);
        c1 += __expf(x.z - M) + __expf(x.w - M);
    }
    float c = c0 + c1;
    #pragma unroll
    for (int off = 1; off < 64; off <<= 1)
        c += __shfl_xor(c, off, 64);
    if (lane == 0) ssum[wave] = c;
    __syncthreads();
    if (tid == 0) {
        float S2 = (ssum[0] + ssum[1]) + (ssum[2] + ssum[3]);
        nll[row] = M + __logf(S2) - lt;
    }
}

// ---------------------------------------------------------------------------
// Kernel 2: per-batch-item category sums/counts (8 blocks).
// ---------------------------------------------------------------------------
__global__ __launch_bounds__(256)
void batch_reduce_kernel(const int* __restrict__ inp,
                         const float* __restrict__ nll,
                         float* __restrict__ part) {
    const int b = blockIdx.x;
    const int tid = threadIdx.x;
    float acc[6] = {0.f, 0.f, 0.f, 0.f, 0.f, 0.f};
    for (int i = tid; i < NS; i += 256) {
        int tok = inp[b * NS + i];
        float v = nll[b * NS + i];
        if (tok == 4)                 { acc[2] += v; acc[3] += 1.f; }   // msk
        else if ((unsigned)tok < 4u)  { acc[4] += v; acc[5] += 1.f; }   // spc
        else                          { acc[0] += v; acc[1] += 1.f; }   // reg
    }
    __shared__ float buf[6][256];
    #pragma unroll
    for (int k = 0; k < 6; ++k) buf[k][tid] = acc[k];
    __syncthreads();
    for (int off = 128; off > 0; off >>= 1) {
        if (tid < off) {
            #pragma unroll
            for (int k = 0; k < 6; ++k) buf[k][tid] += buf[k][tid + off];
        }
        __syncthreads();
    }
    if (tid == 0) {
        #pragma unroll
        for (int k = 0; k < 6; ++k) part[b * 6 + k] = buf[k][0];
    }
}

// ---------------------------------------------------------------------------
// Kernel 3: finalize — exact reference formula.
// ---------------------------------------------------------------------------
__global__ void finalize_kernel(const float* __restrict__ part,
                                float* __restrict__ out) {
    if (threadIdx.x != 0 || blockIdx.x != 0) return;
    const float W[3] = {1.0f, 1.0f, 0.01f};
    float loss_acc = 0.f;
    float sum_m[3] = {0.f, 0.f, 0.f};
    float sum_p[3] = {0.f, 0.f, 0.f};
    for (int b = 0; b < NB; ++b) {
        float num = 0.f, tw = 0.f;
        #pragma unroll
        for (int k = 0; k < 3; ++k) {
            float s = part[b * 6 + 2 * k];
            float c = part[b * 6 + 2 * k + 1];
            float p = (c > 0.f) ? 1.f : 0.f;
            float mean = (c > 0.f) ? (s / c) : 0.f;
            num += mean * W[k] * p;
            tw  += p * W[k];
            sum_m[k] += mean;
            sum_p[k] += p;
        }
        loss_acc += num / tw;
    }
    out[0] = loss_acc / (float)NB;
    #pragma unroll
    for (int k = 0; k < 3; ++k)
        out[1 + k] = (sum_p[k] > 0.f) ? (sum_m[k] / fmaxf(sum_p[k], 1.f)) : 0.f;
}

// ---------------------------------------------------------------------------
extern "C" void kernel_launch(void* const* d_in, const int* in_sizes, int n_in,
                              void* d_out, int out_size, void* d_ws, size_t ws_size,
                              hipStream_t stream) {
    const float* logits = (const float*)d_in[0];   // [B,S,V] f32
    const int*   inp    = (const int*)d_in[1];     // [B,S] i32
    const int*   tgt    = (const int*)d_in[2];     // [B,S] i32
    float* out = (float*)d_out;                    // 4 f32
    float* nll  = (float*)d_ws;                    // B*S floats
    float* part = nll + NB * NS;                   // B*6 floats

    nll_kernel<<<NB * NS, 256, 0, stream>>>(logits, tgt, nll);
    batch_reduce_kernel<<<NB, 256, 0, stream>>>(inp, nll, part);
    finalize_kernel<<<1, 64, 0, stream>>>(part, out);
}